// Round 2
// baseline (236.161 us; speedup 1.0000x reference)
//
#include <hip/hip_runtime.h>

// PositionEncoder: out[b][s][0:512] = x[b][s][:], out[b][s][512:517] = enc(s)
// B=64, S=1024, D=512, H=W=32.  enc[k] = ((x>>(4-k))&1) & !((y>>(4-k))&1),
// y=s>>5, x=s&31  (verified absmax=0.0 rounds 1-3).
//
// Round-5 (R4 bugfix): R4 crashed on an OOB write -- kTotalF4 was computed as
// 8,478,720 but the true count is 65536*517/4 = 8,470,528 (grid 8272, not
// 8280); the extra 8 blocks stored 131 KB past the end of out.
//
// Structure (unchanged from R4): direct one-pass copy, no LDS, no barrier.
// Each thread owns one aligned out-f4 (4-row groups: 4*517*4 B = 8272 B ≡ 0
// mod 16) built from TWO overlapping aligned x-f4 loads + a static 4-case
// shift-select (source misalignment s = xi&3 constant over ~129-thread runs
// -> near-uniform branch). hi-load lines = lo-load lines +16B -> L1/L2 hits,
// no extra HBM traffic. This is the m13 direct-copy structure (6.29 TB/s)
// with an in-register 5-float/row realign.
//
// Evidence log: R1 scalar stream 233.7, R2 LDS staged 234.2, R3 +nt hints
// 224.9 (fills ~80us each dominate top-5; kernel est ~62us at ~4.3 TB/s).
// R4 OOB crash. R5 prediction: kernel -> ~45us, dur_us ~205-210.

typedef float f32x4 __attribute__((ext_vector_type(4)));

static constexpr unsigned kD        = 512;
static constexpr unsigned kDOut     = 517;
static constexpr unsigned kThreads  = 256;
static constexpr unsigned kF4PerThr = 4;
static constexpr unsigned kRows     = 64u * 1024u;               // 65536
static constexpr unsigned kTotalF4  = kRows * kDOut / 4u;        // 8,470,528
static constexpr unsigned kXF4      = kRows * kD / 4u;           // 8,388,608
static_assert(kTotalF4 == 8470528u, "out f4 count");
static_assert(kTotalF4 % (kThreads * kF4PerThr) == 0, "clean grid");

__global__ __launch_bounds__(kThreads) void pe_kernel(
    const float* __restrict__ x, float* __restrict__ out) {
  const unsigned t    = threadIdx.x;
  const unsigned base = blockIdx.x * (kThreads * kF4PerThr);
  const f32x4* __restrict__ x4 = reinterpret_cast<const f32x4*>(x);
  f32x4* __restrict__ o4       = reinterpret_cast<f32x4*>(out);

#pragma unroll
  for (unsigned it = 0; it < kF4PerThr; ++it) {
    const unsigned fi = base + it * kThreads + t;   // coalesced per iteration
    const unsigned o  = fi * 4u;                    // global out float index
    const unsigned r  = o / kDOut;                  // row (magic-mul div)
    const unsigned c  = o - r * kDOut;              // col in [0, 517)
    f32x4 v;
    if (c <= kD - 4u) {
      // fast path (~98.5% of threads): 4 consecutive x floats, same row
      const unsigned xi = r * kD + c;               // dword-aligned src index
      const unsigned a  = xi >> 2;                  // aligned f4 index
      const unsigned s  = xi & 3u;                  // shift within f4
      const unsigned a1 = (a + 1u < kXF4) ? a + 1u : a;  // clamp tail OOB
      const f32x4 lo = __builtin_nontemporal_load(&x4[a]);
      const f32x4 hi = __builtin_nontemporal_load(&x4[a1]);
      switch (s) {                                  // static indices only
        case 0:  v = lo; break;
        case 1:  v.x = lo.y; v.y = lo.z; v.z = lo.w; v.w = hi.x; break;
        case 2:  v.x = lo.z; v.y = lo.w; v.z = hi.x; v.w = hi.y; break;
        default: v.x = lo.w; v.y = hi.x; v.z = hi.y; v.w = hi.z; break;
      }
    } else {
      // boundary path (2 f4s per 517-float row): elementwise, may cross the
      // row boundary and/or land in the 5 encoding columns
#pragma unroll
      for (unsigned j = 0; j < 4u; ++j) {
        const unsigned oo = o + j;
        const unsigned rr = oo / kDOut;
        const unsigned cc = oo - rr * kDOut;
        float val;
        if (cc < kD) {
          val = x[(size_t)rr * kD + cc];
        } else {
          const unsigned k    = cc - kD;            // 0..4
          const unsigned srow = rr & 1023u;
          const unsigned xx = srow & 31u, yy = srow >> 5, sh = 4u - k;
          val = (float)(((xx >> sh) & 1u) & ((~(yy >> sh)) & 1u));
        }
        v[j] = val;
      }
    }
    __builtin_nontemporal_store(v, &o4[fi]);
  }
}

extern "C" void kernel_launch(void* const* d_in, const int* in_sizes, int n_in,
                              void* d_out, int out_size, void* d_ws,
                              size_t ws_size, hipStream_t stream) {
  const float* x = (const float*)d_in[0];
  float* out = (float*)d_out;
  // 8,470,528 out-f4s / (256 thr * 4 f4/thr) = 8272 blocks exactly
  pe_kernel<<<dim3(8272), dim3(kThreads), 0, stream>>>(x, out);
}

// Round 3
// 231.156 us; speedup vs baseline: 1.0217x; 1.0217x over previous
//
#include <hip/hip_runtime.h>

// PositionEncoder: out[b][s][0:512] = x[b][s][:], out[b][s][512:517] = enc(s)
// B=64, S=1024, D=512, H=W=32.  enc[k] = ((x>>(4-k))&1) & !((y>>(4-k))&1),
// y=s>>5, x=s&31  (verified absmax=0.0 R1-R3, R5).
//
// Round-6: single-load realign via cross-lane shuffle.
// R5 post-mortem: direct copy with TWO overlapping global loads per out-f4
// regressed 225->236 us -- doubled VMEM issue/L1 traffic is the cost currency
// on this mixed-stream copy. Here: hi_f4(lane i) == lo_f4(lane i+1) because
// the row shift s=(-r)&3 is per-row constant and fast-path lanes never cross
// a row to their neighbor (c<=508 => c+4<=512). So: one aligned nt load,
// hi = shfl_down(lo,1) (4x ds_bpermute), lane-63 patched by a 1-lane
// predicated load. No LDS array, no barrier, aligned nt stores (4-row groups
// = 8272 B = 16B-aligned). Boundary f4s (2 per row, ~1.5%) take the R5
// verified elementwise path.
//
// OOB proof: clamp lo index (only last-row boundary lanes exceed kXF4; value
// unused). Needed shfl sources always have c'<=512 and r'=r, and for
// s!=0 rows c' mod 4 != 0 => c'<512 => a' <= 128r+127 < kXF4.
//
// Evidence log: R1 scalar 233.7 | R2 LDS 234.2 | R3 LDS+nt 224.9 (best) |
// R4 OOB crash | R5 dual-load 236.2. R6 prediction: dur ~213-218.

typedef float f32x4 __attribute__((ext_vector_type(4)));

static constexpr unsigned kD        = 512;
static constexpr unsigned kDOut     = 517;
static constexpr unsigned kThreads  = 256;
static constexpr unsigned kF4PerThr = 4;
static constexpr unsigned kRows     = 64u * 1024u;               // 65536
static constexpr unsigned kTotalF4  = kRows * kDOut / 4u;        // 8,470,528
static constexpr unsigned kXF4      = kRows * kD / 4u;           // 8,388,608
static_assert(kTotalF4 == 8470528u, "out f4 count");
static_assert(kTotalF4 % (kThreads * kF4PerThr) == 0, "clean grid");

__global__ __launch_bounds__(kThreads) void pe_kernel(
    const float* __restrict__ x, float* __restrict__ out) {
  const unsigned t    = threadIdx.x;
  const unsigned lane = t & 63u;
  const unsigned base = blockIdx.x * (kThreads * kF4PerThr);
  const f32x4* __restrict__ x4 = reinterpret_cast<const f32x4*>(x);
  f32x4* __restrict__ o4       = reinterpret_cast<f32x4*>(out);

#pragma unroll
  for (unsigned it = 0; it < kF4PerThr; ++it) {
    const unsigned fi = base + it * kThreads + t;   // coalesced per iteration
    const unsigned o  = fi * 4u;                    // global out float index
    const unsigned r  = o / kDOut;                  // row (magic-mul div)
    const unsigned c  = o - r * kDOut;              // col in [0, 517)
    const unsigned xi = r * kD + c;                 // source float index
    const unsigned a  = xi >> 2;                    // aligned f4 index
    const unsigned s  = xi & 3u;                    // shift (== (-r)&3)
    const unsigned ac = (a < kXF4) ? a : (kXF4 - 1u);  // clamp (unused lanes)

    // one aligned vector load per out-f4 -- the only bulk read
    const f32x4 lo = __builtin_nontemporal_load(&x4[ac]);

    // hi = next lane's lo (valid for all fast-path lanes except lane 63)
    f32x4 hi;
    hi.x = __shfl_down(lo.x, 1, 64);
    hi.y = __shfl_down(lo.y, 1, 64);
    hi.z = __shfl_down(lo.z, 1, 64);
    hi.w = __shfl_down(lo.w, 1, 64);

    const bool fast = (c <= kD - 4u);
    if (lane == 63u && fast && s != 0u) {           // 1-lane patch load
      const unsigned a1 = (a + 1u < kXF4) ? a + 1u : kXF4 - 1u;
      hi = __builtin_nontemporal_load(&x4[a1]);
    }

    f32x4 v;
    if (fast) {
      switch (s) {                                  // static indices only
        case 0:  v = lo; break;
        case 1:  v.x = lo.y; v.y = lo.z; v.z = lo.w; v.w = hi.x; break;
        case 2:  v.x = lo.z; v.y = lo.w; v.z = hi.x; v.w = hi.y; break;
        default: v.x = lo.w; v.y = hi.x; v.z = hi.y; v.w = hi.z; break;
      }
    } else {
      // boundary path (2 f4s per 517-float row): elementwise, may cross the
      // row boundary and/or land in the 5 encoding columns
#pragma unroll
      for (unsigned j = 0; j < 4u; ++j) {
        const unsigned oo = o + j;
        const unsigned rr = oo / kDOut;
        const unsigned cc = oo - rr * kDOut;
        float val;
        if (cc < kD) {
          val = x[(size_t)rr * kD + cc];
        } else {
          const unsigned k    = cc - kD;            // 0..4
          const unsigned srow = rr & 1023u;
          const unsigned xx = srow & 31u, yy = srow >> 5, sh = 4u - k;
          val = (float)(((xx >> sh) & 1u) & ((~(yy >> sh)) & 1u));
        }
        v[j] = val;
      }
    }
    __builtin_nontemporal_store(v, &o4[fi]);
  }
}

extern "C" void kernel_launch(void* const* d_in, const int* in_sizes, int n_in,
                              void* d_out, int out_size, void* d_ws,
                              size_t ws_size, hipStream_t stream) {
  const float* x = (const float*)d_in[0];
  float* out = (float*)d_out;
  // 8,470,528 out-f4s / (256 thr * 4 f4/thr) = 8272 blocks exactly
  pe_kernel<<<dim3(8272), dim3(kThreads), 0, stream>>>(x, out);
}